// Round 1
// baseline (448.042 us; speedup 1.0000x reference)
//
#include <hip/hip_runtime.h>

#define NROWS   131072      // 64*2048 rows
#define DIM     64
#define K       1024
#define QELEMS  8388608     // NROWS*DIM
#define BLOCK   128
#define PAD     65          // LDS row stride (+1 pad: bank = (r+i)%32, 2-way = free)

// se[j] = fp32 pairwise-8 sum of weight[j][i]^2, matching np.sum(w*w, axis=1)
__global__ void vq_se_kernel(const float* __restrict__ w, float* __restrict__ se) {
    int j = blockIdx.x * blockDim.x + threadIdx.x;
    if (j < K) {
        #pragma clang fp contract(off)
        const float* e = w + j * DIM;
        float r[8];
        #pragma unroll
        for (int k = 0; k < 8; ++k) r[k] = e[k] * e[k];
        #pragma unroll
        for (int i = 8; i < DIM; i += 8)
            #pragma unroll
            for (int k = 0; k < 8; ++k) r[k] += e[i + k] * e[i + k];
        se[j] = ((r[0] + r[1]) + (r[2] + r[3])) + ((r[4] + r[5]) + (r[6] + r[7]));
    }
}

__global__ __launch_bounds__(BLOCK) void vq_main_kernel(
    const float* __restrict__ x, const float* __restrict__ w,
    const float* __restrict__ se, float* __restrict__ out) {
    __shared__ float xs[BLOCK * PAD];
    __shared__ float psum[BLOCK / 64];
    const int tid = threadIdx.x;
    const long long rowBase = (long long)blockIdx.x * BLOCK;

    // Stage x tile, coalesced float4 loads (base is 16B-aligned: rowBase*DIM*4 mult of 32KB)
    {
        const float4* x4 = (const float4*)(x + rowBase * DIM);
        #pragma unroll
        for (int it = 0; it < (BLOCK * DIM / 4) / BLOCK; ++it) {
            int idx = it * BLOCK + tid;
            float4 v = x4[idx];
            int r = idx >> 4;      // 16 float4 per row
            int c = idx & 15;
            float* dst = &xs[r * PAD + c * 4];
            dst[0] = v.x; dst[1] = v.y; dst[2] = v.z; dst[3] = v.w;
        }
    }
    __syncthreads();

    // Each lane owns one row in registers
    float xr[DIM];
    #pragma unroll
    for (int i = 0; i < DIM; ++i) xr[i] = xs[tid * PAD + i];

    // c = fp32 pairwise-8 sum of x^2 (numpy np.sum emulation, no contraction)
    float cr;
    {
        #pragma clang fp contract(off)
        float r[8];
        #pragma unroll
        for (int k = 0; k < 8; ++k) r[k] = xr[k] * xr[k];
        #pragma unroll
        for (int i = 8; i < DIM; i += 8)
            #pragma unroll
            for (int k = 0; k < 8; ++k) r[k] += xr[i + k] * xr[i + k];
        cr = ((r[0] + r[1]) + (r[2] + r[3])) + ((r[4] + r[5]) + (r[6] + r[7]));
    }

    // Argmin over codes; e row is wave-uniform -> scalar loads expected.
    float bestd = 3.402823466e38f;
    int bestj = 0;
    for (int j = 0; j < K; ++j) {
        const float* __restrict__ e = w + j * DIM;
        float a0 = 0.f, a1 = 0.f, a2 = 0.f, a3 = 0.f;   // 4 chains for ILP
        #pragma unroll
        for (int i = 0; i < DIM; i += 4) {
            a0 = fmaf(xr[i + 0], e[i + 0], a0);
            a1 = fmaf(xr[i + 1], e[i + 1], a1);
            a2 = fmaf(xr[i + 2], e[i + 2], a2);
            a3 = fmaf(xr[i + 3], e[i + 3], a3);
        }
        float dot = (a0 + a1) + (a2 + a3);
        float d;
        {
            #pragma clang fp contract(off)
            float t = cr + se[j];    // fl(c + se): matches (A+B) elementwise rounding
            d = t - 2.0f * dot;      // fl(t - 2*dot): matches (-2*matmul) subtract
        }
        if (d < bestd) { bestd = d; bestj = j; }  // strict < == first-index tie-break
    }

    __syncthreads();   // all xs reads done in every wave; safe to reuse as qst buffer

    // Gather chosen code, compute q_st = fl(x + fl(q-x)) and loss partial
    float part = 0.f;
    {
        #pragma clang fp contract(off)
        const float* e = w + bestj * DIM;  // divergent gather, L2-hot
        #pragma unroll
        for (int i = 0; i < DIM; ++i) {
            float q = e[i];
            float diff = q - xr[i];
            part += diff * diff;
            xs[tid * PAD + i] = xr[i] + diff;
        }
    }
    __syncthreads();

    // Coalesced scalar stores (out+1 is not 16B-aligned, so no float4)
    {
        float* qout = out + 1 + rowBase * DIM;
        #pragma unroll 8
        for (int it = 0; it < DIM; ++it) {
            int idx = it * BLOCK + tid;
            int r = idx >> 6;          // DIM floats per row
            int c = idx & 63;
            qout[idx] = xs[r * PAD + c];
        }
    }

    // Index output (as float)
    out[1 + (long long)QELEMS + rowBase + tid] = (float)bestj;

    // Loss: wave shuffle reduce -> block -> one atomic
    for (int off = 32; off > 0; off >>= 1) part += __shfl_down(part, off, 64);
    int wid = tid >> 6, lane = tid & 63;
    if (lane == 0) psum[wid] = part;
    __syncthreads();
    if (tid == 0) {
        float s = 0.f;
        #pragma unroll
        for (int wv = 0; wv < BLOCK / 64; ++wv) s += psum[wv];
        atomicAdd(out, s * (1.25f / 8388608.0f));  // loss = 1.25 * mean((q-x)^2)
    }
}

extern "C" void kernel_launch(void* const* d_in, const int* in_sizes, int n_in,
                              void* d_out, int out_size, void* d_ws, size_t ws_size,
                              hipStream_t stream) {
    const float* x = (const float*)d_in[0];
    const float* w = (const float*)d_in[1];
    float* out = (float*)d_out;
    float* se = (float*)d_ws;   // K floats of scratch

    hipMemsetAsync(d_out, 0, sizeof(float), stream);          // zero loss accumulator
    vq_se_kernel<<<K / 256, 256, 0, stream>>>(w, se);
    vq_main_kernel<<<NROWS / BLOCK, BLOCK, 0, stream>>>(x, w, se, out);
}

// Round 3
// 292.221 us; speedup vs baseline: 1.5332x; 1.5332x over previous
//
#include <hip/hip_runtime.h>

#define NROWS   131072
#define DIM     64
#define K       1024
#define QOFF    1
#define IDXOFF  8388609        // 1 + NROWS*DIM
#define MARGIN  1.5e-4f

typedef float  f32x4  __attribute__((ext_vector_type(4)));
typedef __bf16 bf16x8 __attribute__((ext_vector_type(8)));

// ---------- np-exact arithmetic (validated in R1: absmax 0.0) ----------
__device__ __forceinline__ float np_norm64(const float* v) {
    #pragma clang fp contract(off)
    float r[8];
    #pragma unroll
    for (int k = 0; k < 8; ++k) r[k] = v[k] * v[k];
    #pragma unroll
    for (int i = 8; i < 64; i += 8)
        #pragma unroll
        for (int k = 0; k < 8; ++k) r[k] += v[i + k] * v[i + k];
    return ((r[0] + r[1]) + (r[2] + r[3])) + ((r[4] + r[5]) + (r[6] + r[7]));
}
__device__ __forceinline__ float exact_dot64(const float* xr, const float* __restrict__ e) {
    float a0 = 0.f, a1 = 0.f, a2 = 0.f, a3 = 0.f;
    #pragma unroll
    for (int i = 0; i < 64; i += 4) {
        a0 = fmaf(xr[i + 0], e[i + 0], a0);
        a1 = fmaf(xr[i + 1], e[i + 1], a1);
        a2 = fmaf(xr[i + 2], e[i + 2], a2);
        a3 = fmaf(xr[i + 3], e[i + 3], a3);
    }
    return (a0 + a1) + (a2 + a3);
}
__device__ __forceinline__ float exact_d(float cr, float sej, float dot) {
    #pragma clang fp contract(off)
    float t = cr + sej;
    return t - 2.0f * dot;
}

// ---------- prep: W -> bf16 hi/lo (plain row-major) + np-exact se ----------
__global__ void vq_prep(const float* __restrict__ w, unsigned short* __restrict__ Ghi,
                        unsigned short* __restrict__ Glo, float* __restrict__ se) {
    int gid = blockIdx.x * 256 + threadIdx.x;       // 0..8191
    int n = gid >> 3, s = gid & 7;
    const float* row = w + n * 64 + s * 8;
    bf16x8 h8, l8;
    #pragma unroll
    for (int j = 0; j < 8; ++j) {
        float xv = row[j];
        __bf16 hb = (__bf16)xv;
        h8[j] = hb;
        l8[j] = (__bf16)(xv - (float)hb);
    }
    *(bf16x8*)(Ghi + n * 64 + s * 8) = h8;
    *(bf16x8*)(Glo + n * 64 + s * 8) = l8;
    if (gid < K) {
        #pragma clang fp contract(off)
        const float* e = w + gid * 64;
        float r[8];
        #pragma unroll
        for (int k2 = 0; k2 < 8; ++k2) r[k2] = e[k2] * e[k2];
        #pragma unroll
        for (int i = 8; i < 64; i += 8)
            #pragma unroll
            for (int k2 = 0; k2 < 8; ++k2) r[k2] += e[i + k2] * e[i + k2];
        se[gid] = ((r[0] + r[1]) + (r[2] + r[3])) + ((r[4] + r[5]) + (r[6] + r[7]));
    }
}

// ---------- screen: split-bf16 MFMA distances + top-3 + decided q/loss ----------
// block = 256 (4 waves); wave = 32 rows (2 M-tiles); block = 128 rows; grid = 1024
#define INSERT_IDX(V, J)                                               \
    do {                                                               \
        bool c1 = (V) < v1[mt][r];                                     \
        bool c2 = (V) < v2[mt][r];                                     \
        bool c3 = (V) < v3[mt][r];                                     \
        float ov1 = v1[mt][r]; int oj1 = j1[mt][r];                    \
        float ov2 = v2[mt][r];                                         \
        v3[mt][r] = c2 ? ov2 : (c3 ? (V) : v3[mt][r]);                 \
        v2[mt][r] = c1 ? ov1 : (c2 ? (V) : ov2);                       \
        j2[mt][r] = c1 ? oj1 : (c2 ? (J) : j2[mt][r]);                 \
        v1[mt][r] = c1 ? (V) : ov1;                                    \
        j1[mt][r] = c1 ? (J) : oj1;                                    \
    } while (0)

__global__ __launch_bounds__(256, 4) void vq_screen(
    const float* __restrict__ x, const float* __restrict__ w,
    const unsigned short* __restrict__ Ghi, const unsigned short* __restrict__ Glo,
    const float* __restrict__ se, float* __restrict__ out,
    int* __restrict__ counters, int* __restrict__ pairList, int* __restrict__ fullList) {
    __shared__ f32x4 sB[2048];          // 32 KB: [0,1024) = hi chunk, [1024,2048) = lo chunk
    __shared__ int jrow[128];
    const int tid  = threadIdx.x;
    const int wave = tid >> 6, lane = tid & 63;
    const int quad = lane >> 4, m16 = lane & 15;
    const int rowBlk = blockIdx.x * 128;
    const int wrow0  = rowBlk + wave * 32;

    // A fragments: X rows -> hi/lo bf16, resident in VGPRs for the whole K scan.
    // Layout (verified m120/m89): A[m = lane&15][k = quad*8 + j], k-chunk c covers k = 32c..32c+31.
    bf16x8 Ah[2][2], Al[2][2];
    #pragma unroll
    for (int mt = 0; mt < 2; ++mt)
        #pragma unroll
        for (int c = 0; c < 2; ++c) {
            const float* p = x + (wrow0 + mt * 16 + m16) * 64 + c * 32 + quad * 8;
            f32x4 u0 = *(const f32x4*)p;
            f32x4 u1 = *(const f32x4*)(p + 4);
            #pragma unroll
            for (int j = 0; j < 8; ++j) {
                float xv = (j < 4) ? u0[j] : u1[j - 4];
                __bf16 hb = (__bf16)xv;
                Ah[mt][c][j] = hb;
                Al[mt][c][j] = (__bf16)(xv - (float)hb);
            }
        }

    float v1[2][4], v2[2][4], v3[2][4];
    int   j1[2][4], j2[2][4];
    #pragma unroll
    for (int mt = 0; mt < 2; ++mt)
        #pragma unroll
        for (int r = 0; r < 4; ++r) {
            v1[mt][r] = 3.402823466e38f; v2[mt][r] = 3.402823466e38f; v3[mt][r] = 3.402823466e38f;
            j1[mt][r] = 0; j2[mt][r] = 0;
        }

    for (int ch = 0; ch < 8; ++ch) {
        __syncthreads();
        // stage 128-code chunk (hi+lo, 32 KB) with bank-swizzle baked into LDS placement:
        // sB[hl*1024 + n*8 + ((s + (n&7)) & 7)] = W'[code=ch*128+n][8 bf16 at sub-chunk s]
        #pragma unroll
        for (int it = 0; it < 8; ++it) {
            int flat = it * 256 + tid;
            int hl = flat >> 10;
            int u  = flat & 1023;
            int n  = u >> 3, s = u & 7;
            const unsigned short* src = (hl ? Glo : Ghi) + (ch * 128 + n) * 64 + s * 8;
            sB[hl * 1024 + n * 8 + ((s + (n & 7)) & 7)] = *(const f32x4*)src;
        }
        __syncthreads();

        for (int nt = 0; nt < 8; ++nt) {
            int nl  = nt * 16 + m16;
            int swz = nl & 7;
            bf16x8 Bh0 = __builtin_bit_cast(bf16x8, sB[nl * 8 + ((quad + swz) & 7)]);
            bf16x8 Bh1 = __builtin_bit_cast(bf16x8, sB[nl * 8 + ((4 + quad + swz) & 7)]);
            bf16x8 Bl0 = __builtin_bit_cast(bf16x8, sB[1024 + nl * 8 + ((quad + swz) & 7)]);
            bf16x8 Bl1 = __builtin_bit_cast(bf16x8, sB[1024 + nl * 8 + ((4 + quad + swz) & 7)]);
            int jn = ch * 128 + nl;
            float sen = se[jn];
            #pragma unroll
            for (int mt = 0; mt < 2; ++mt) {
                f32x4 acc = {0.f, 0.f, 0.f, 0.f};
                acc = __builtin_amdgcn_mfma_f32_16x16x32_bf16(Ah[mt][0], Bh0, acc, 0, 0, 0);
                acc = __builtin_amdgcn_mfma_f32_16x16x32_bf16(Ah[mt][1], Bh1, acc, 0, 0, 0);
                acc = __builtin_amdgcn_mfma_f32_16x16x32_bf16(Al[mt][0], Bh0, acc, 0, 0, 0);
                acc = __builtin_amdgcn_mfma_f32_16x16x32_bf16(Al[mt][1], Bh1, acc, 0, 0, 0);
                acc = __builtin_amdgcn_mfma_f32_16x16x32_bf16(Ah[mt][0], Bl0, acc, 0, 0, 0);
                acc = __builtin_amdgcn_mfma_f32_16x16x32_bf16(Ah[mt][1], Bl1, acc, 0, 0, 0);
                #pragma unroll
                for (int r = 0; r < 4; ++r) {
                    float v = fmaf(-2.0f, acc[r], sen);
                    INSERT_IDX(v, jn);
                }
            }
        }
    }

    // cross-lane top-3 merge over the 16 cols of each row (C layout: col=lane&15, row=quad*4+reg)
    #pragma unroll
    for (int mask = 1; mask <= 8; mask <<= 1) {
        #pragma unroll
        for (int mt = 0; mt < 2; ++mt)
            #pragma unroll
            for (int r = 0; r < 4; ++r) {
                float bv1 = __shfl_xor(v1[mt][r], mask, 64);
                int   bj1 = __shfl_xor(j1[mt][r], mask, 64);
                float bv2 = __shfl_xor(v2[mt][r], mask, 64);
                int   bj2 = __shfl_xor(j2[mt][r], mask, 64);
                float bv3 = __shfl_xor(v3[mt][r], mask, 64);
                INSERT_IDX(bv1, bj1);
                INSERT_IDX(bv2, bj2);
                v3[mt][r] = fminf(v3[mt][r], bv3);
            }
    }

    if (m16 == 0) {
        #pragma unroll
        for (int mt = 0; mt < 2; ++mt)
            #pragma unroll
            for (int r = 0; r < 4; ++r) {
                int rowL = wave * 32 + mt * 16 + quad * 4 + r;
                int rowG = rowBlk + rowL;
                if (v2[mt][r] - v1[mt][r] > MARGIN) {        // provably unique winner
                    out[IDXOFF + rowG] = (float)j1[mt][r];
                    jrow[rowL] = j1[mt][r];
                } else {
                    jrow[rowL] = -1;
                    if (v3[mt][r] - v1[mt][r] > MARGIN) {    // winner in {j1,j2}
                        int c = atomicAdd(&counters[0], 1);
                        pairList[3 * c] = rowG; pairList[3 * c + 1] = j1[mt][r]; pairList[3 * c + 2] = j2[mt][r];
                    } else {                                  // rare: full rescan
                        int c = atomicAdd(&counters[1], 1);
                        fullList[c] = rowG;
                    }
                }
            }
    }
    __syncthreads();

    // q_st + loss for decided rows, coalesced: lane = dim, one row at a time
    float part = 0.f;
    for (int i = 0; i < 32; ++i) {
        int jr = jrow[wave * 32 + i];      // wave-uniform
        if (jr < 0) continue;
        int rowG = wrow0 + i;
        {
            #pragma clang fp contract(off)
            float xv = x[rowG * 64 + lane];
            float wv = w[jr * 64 + lane];
            float diff = wv - xv;
            part += diff * diff;
            out[QOFF + rowG * 64 + lane] = xv + diff;
        }
    }
    for (int off = 32; off > 0; off >>= 1) part += __shfl_down(part, off, 64);
    if (lane == 0) atomicAdd(out, part * (1.25f / 8388608.0f));
}

// ---------- finish: exact pair-compares (per thread) + full rescans (per wave) ----------
__global__ __launch_bounds__(256) void vq_finish(
    const float* __restrict__ x, const float* __restrict__ w, const float* __restrict__ se,
    float* __restrict__ out, const int* __restrict__ counters,
    const int* __restrict__ pairList, const int* __restrict__ fullList) {
    const int tid = threadIdx.x;
    const int lane = tid & 63, wave = tid >> 6;
    const int nPair = counters[0], nFull = counters[1];
    const int gthread = blockIdx.x * 256 + tid, nThreads = gridDim.x * 256;
    const int gwave = blockIdx.x * 4 + wave,   nWaves = gridDim.x * 4;
    float part = 0.f;

    // Phase A: winner in {ja, jb}; exact compare with np first-index tie rule
    for (int i = gthread; i < nPair; i += nThreads) {
        int row = pairList[3 * i], ja = pairList[3 * i + 1], jb = pairList[3 * i + 2];
        if (ja > jb) { int t = ja; ja = jb; jb = t; }
        float xr[64];
        const f32x4* xp = (const f32x4*)(x + row * 64);
        #pragma unroll
        for (int t = 0; t < 16; ++t) {
            f32x4 v = xp[t];
            xr[4 * t] = v[0]; xr[4 * t + 1] = v[1]; xr[4 * t + 2] = v[2]; xr[4 * t + 3] = v[3];
        }
        float cr = np_norm64(xr);
        float da = exact_d(cr, se[ja], exact_dot64(xr, w + ja * 64));
        float db = exact_d(cr, se[jb], exact_dot64(xr, w + jb * 64));
        int win = (db < da) ? jb : ja;
        out[IDXOFF + row] = (float)win;
        const float* e = w + win * 64;
        {
            #pragma clang fp contract(off)
            #pragma unroll
            for (int i2 = 0; i2 < 64; ++i2) {
                float diff = e[i2] - xr[i2];
                part += diff * diff;
                out[QOFF + row * 64 + i2] = xr[i2] + diff;
            }
        }
    }

    // Phase B: full exact rescan, one row per wave (16 codes per lane)
    for (int i = gwave; i < nFull; i += nWaves) {
        int row = fullList[i];
        float xr[64];
        const f32x4* xp = (const f32x4*)(x + row * 64);
        #pragma unroll
        for (int t = 0; t < 16; ++t) {
            f32x4 v = xp[t];
            xr[4 * t] = v[0]; xr[4 * t + 1] = v[1]; xr[4 * t + 2] = v[2]; xr[4 * t + 3] = v[3];
        }
        float cr = np_norm64(xr);
        float bd = 3.402823466e38f; int bj = 0;
        for (int t = 0; t < 16; ++t) {
            int j = lane * 16 + t;
            float d = exact_d(cr, se[j], exact_dot64(xr, w + j * 64));
            if (d < bd) { bd = d; bj = j; }
        }
        for (int mask = 1; mask < 64; mask <<= 1) {
            float od = __shfl_xor(bd, mask, 64);
            int   oj = __shfl_xor(bj, mask, 64);
            if (od < bd || (od == bd && oj < bj)) { bd = od; bj = oj; }
        }
        {
            #pragma clang fp contract(off)
            float xv = x[row * 64 + lane];
            float wv = w[bj * 64 + lane];
            float diff = wv - xv;
            part += diff * diff;
            out[QOFF + row * 64 + lane] = xv + diff;
        }
        if (lane == 0) out[IDXOFF + row] = (float)bj;
    }

    for (int off = 32; off > 0; off >>= 1) part += __shfl_down(part, off, 64);
    if (lane == 0 && part != 0.f) atomicAdd(out, part * (1.25f / 8388608.0f));
}

extern "C" void kernel_launch(void* const* d_in, const int* in_sizes, int n_in,
                              void* d_out, int out_size, void* d_ws, size_t ws_size,
                              hipStream_t stream) {
    const float* x = (const float*)d_in[0];
    const float* w = (const float*)d_in[1];
    float* out = (float*)d_out;

    unsigned short* Ghi = (unsigned short*)d_ws;                 // 128 KB
    unsigned short* Glo = Ghi + 65536;                           // 128 KB
    float* se = (float*)(Glo + 65536);                           // 4 KB  (off 262144)
    int* counters = (int*)((char*)d_ws + 266240);                // 8 B
    int* pairList = (int*)((char*)d_ws + 266248);                // <= 1.5 MB
    int* fullList = pairList + 3 * NROWS;                        // <= 512 KB

    (void)hipMemsetAsync(out, 0, sizeof(float), stream);         // loss accumulator
    (void)hipMemsetAsync(counters, 0, 2 * sizeof(int), stream);
    vq_prep<<<32, 256, 0, stream>>>(w, Ghi, Glo, se);
    vq_screen<<<1024, 256, 0, stream>>>(x, w, Ghi, Glo, se, out, counters, pairList, fullList);
    vq_finish<<<128, 256, 0, stream>>>(x, w, se, out, counters, pairList, fullList);
}